// Round 7
// baseline (36.919 us; speedup 1.0000x reference)
//
#include <hip/hip_runtime.h>
#include <hip/hip_bf16.h>
#include <math.h>

#define BB 32
#define SS 256
#define DD 128
#define KK 16
#define VV 50000
#define SK (SS*KK)   // 4096

typedef __attribute__((ext_vector_type(8))) short bf16x8;
typedef __attribute__((ext_vector_type(4))) float f32x4;
typedef __attribute__((ext_vector_type(16))) float f32x16;
typedef unsigned short ushort_t;

static __device__ __forceinline__ short f2bf(float f) {
    __hip_bfloat16 h = __float2bfloat16(f);   // compiler fuses pairs -> v_cvt_pk_bf16_f32
    return *(short*)&h;
}

// byte offset of element (row, d) in a [R][128] bf16 LDS tile, XOR-swizzled:
// 16B-chunk index c = d/8 -> c ^ (row & 15). 2 lanes/bank on frag reads = free.
static __device__ __forceinline__ int lds_off(int row, int d) {
    return row * 256 + ((d * 2) ^ ((row & 15) << 4));
}

static __device__ __forceinline__ void gload_lds16(const void* g, void* lds) {
    __builtin_amdgcn_global_load_lds(
        (const __attribute__((address_space(1))) unsigned int*)g,
        (__attribute__((address_space(3))) unsigned int*)lds, 16, 0, 0);
}

// ---------------- convert kernel: latent only, fp32 -> bf16 -----------------
#define NLAT (BB*SS*DD)       // 1,048,576
#define NCHUNK_LAT (NLAT/8)

__global__ __launch_bounds__(256)
void convert_lat_kernel(const float* __restrict__ latent,
                        ushort_t* __restrict__ ws_lat)
{
    int i = blockIdx.x * 256 + threadIdx.x;
    if (i >= NCHUNK_LAT) return;
    const float* src = latent + (size_t)i * 8;
    float f[8];
    *(float4*)(f + 0) = ((const float4*)src)[0];
    *(float4*)(f + 4) = ((const float4*)src)[1];
    short o[8];
    #pragma unroll
    for (int e = 0; e < 8; ++e) o[e] = f2bf(f[e]);
    *(bf16x8*)(ws_lat + (size_t)i * 8) = *(bf16x8*)o;
}

// ---------------- main kernel ------------------------------------------------
// grid (32 n-tiles, 2 m-halves, 32 batches) = 2048 blocks; 4 waves/block.
// Per block: 128 latent rows staged ONCE to LDS (32 KB, single buffer, one
// barrier); per wave 32 candidate rows gathered fp32->bf16 into registers.
// Then 2 m-subtiles computed back-to-back with zero further barriers.
#define MTB 128   // latent rows per block
#define NT  128   // candidate rows per block

__global__ __launch_bounds__(256, 5)
void neg_loss_main(const ushort_t* __restrict__ lat_bf,   // [B,S,D] bf16 (ws)
                   const int*      __restrict__ labels,   // [B,S]
                   const int*      __restrict__ samples,  // [B,S*(K-1)]
                   const float*    __restrict__ embed,    // [V,D] fp32
                   float* __restrict__ out)               // [B,S,S]
{
    __shared__ char ldsA[MTB * 256];   // 32 KB

    const int b    = blockIdx.z;
    const int m0   = blockIdx.y * MTB;
    const int n0   = blockIdx.x * NT;
    const int tid  = threadIdx.x;
    const int wave = tid >> 6;
    const int lane = tid & 63;
    const int q    = lane & 15;
    const int sub  = lane >> 4;
    const int l31  = lane & 31;
    const int hi   = lane >> 5;

    // ---- stage A first (independent of gather): 128 rows, 8 chunks/thread --
    #pragma unroll
    for (int t = 0; t < 8; ++t) {
        const int r0 = wave * 32 + t * 4;
        const int r  = r0 + sub;
        const ushort_t* src = lat_bf + ((size_t)(b * SS + m0 + r) * DD)
                                     + ((q ^ (r & 15)) << 3);
        gload_lds16(src, ldsA + r0 * 256);
    }

    // ---- candidate index for this lane's B row ----
    const int rB  = wave * 32 + l31;
    const int gc  = n0 + rB;
    const int j   = gc >> 4;
    const int k   = gc & 15;
    const int idx = (k < 15)
        ? samples[(size_t)b * (SS * (KK - 1)) + j * (KK - 1) + k]
        : labels[b * SS + j];

    // ---- B gather: this lane's half-row (k = ks*16 + hi*8 + e), fp32 ----
    const float* rowp = embed + (size_t)idx * DD + hi * 8;
    f32x4 fb[16];
    #pragma unroll
    for (int ks = 0; ks < 8; ++ks) {
        fb[2 * ks]     = *(const f32x4*)(rowp + ks * 16);
        fb[2 * ks + 1] = *(const f32x4*)(rowp + ks * 16 + 4);
    }
    bf16x8 av[8];
    #pragma unroll
    for (int ks = 0; ks < 8; ++ks) {
        short t8[8];
        #pragma unroll
        for (int e = 0; e < 4; ++e) t8[e]     = f2bf(fb[2 * ks][e]);
        #pragma unroll
        for (int e = 0; e < 4; ++e) t8[4 + e] = f2bf(fb[2 * ks + 1][e]);
        av[ks] = *(bf16x8*)t8;
    }

    __syncthreads();   // A staged (vmcnt drained); only barrier in the kernel

    const int jb = (n0 >> 4) + wave * 2;

    #pragma unroll
    for (int mt = 0; mt < 2; ++mt) {
        // ---- MFMA 32x32x16, swapped: D[row=cand][col=lat] ----
        f32x16 acc0 = {}, acc1 = {};
        #pragma unroll
        for (int ks = 0; ks < 8; ++ks) {
            const int d = ks * 16 + hi * 8;
            bf16x8 bv0 = *(const bf16x8*)(ldsA + lds_off(mt * 64 + l31, d));
            bf16x8 bv1 = *(const bf16x8*)(ldsA + lds_off(mt * 64 + 32 + l31, d));
            acc0 = __builtin_amdgcn_mfma_f32_32x32x16_bf16(av[ks], bv0, acc0, 0, 0, 0);
            acc1 = __builtin_amdgcn_mfma_f32_32x32x16_bf16(av[ks], bv1, acc1, 0, 0, 0);
        }

        // ---- fused LSE epilogue ----
        // D rows/lane: (reg&3)+8*(reg>>2)+4*hi. group0 = regs0-7, group1 = 8-15.
        #pragma unroll
        for (int f = 0; f < 2; ++f) {
            const f32x16 v = f ? acc1 : acc0;
            float pm0 = fmaxf(fmaxf(fmaxf(v[0], v[1]), fmaxf(v[2], v[3])),
                              fmaxf(fmaxf(v[4], v[5]), fmaxf(v[6], v[7])));
            float pm1 = fmaxf(fmaxf(fmaxf(v[8], v[9]), fmaxf(v[10], v[11])),
                              fmaxf(fmaxf(v[12], v[13]), fmaxf(v[14], v[15])));
            float om0 = fmaxf(pm0, __shfl_xor(pm0, 32));
            float om1 = fmaxf(pm1, __shfl_xor(pm1, 32));
            float e0 = ((__expf(v[0] - om0) + __expf(v[1] - om0))
                      + (__expf(v[2] - om0) + __expf(v[3] - om0)))
                     + ((__expf(v[4] - om0) + __expf(v[5] - om0))
                      + (__expf(v[6] - om0) + __expf(v[7] - om0)));
            float e1 = ((__expf(v[8]  - om1) + __expf(v[9]  - om1))
                      + (__expf(v[10] - om1) + __expf(v[11] - om1)))
                     + ((__expf(v[12] - om1) + __expf(v[13] - om1))
                      + (__expf(v[14] - om1) + __expf(v[15] - om1)));
            float s0 = e0 + __shfl_xor(e0, 32);
            float s1 = e1 + __shfl_xor(e1, 32);
            float pos0 = __shfl_xor(v[7], 32);  // hi=0 lanes get cand row 15
            float pos1 = v[15];                 // hi=1 lanes hold row 31
            const float pos = hi ? pos1 : pos0;
            const float om  = hi ? om1  : om0;
            const float s   = hi ? s1   : s0;
            const int i = m0 + mt * 64 + f * 32 + l31;
            out[((size_t)b * SS + i) * SS + (jb + hi)] = pos - om - __logf(s);
        }
    }
}

// ---------------- fallback (fp32 gather + in-kernel convert) ----------------
__global__ __launch_bounds__(256)
void neg_loss_fallback(const float* __restrict__ latent,
                       const int*   __restrict__ labels,
                       const int*   __restrict__ samples,
                       const float* __restrict__ embed,
                       float* __restrict__ out)
{
    __shared__ char ldsA[64 * 256];
    __shared__ char ldsB[64 * 256];

    const int b   = blockIdx.z;
    const int m0  = blockIdx.y * 64;
    const int n0  = blockIdx.x * 64;
    const int tid = threadIdx.x;

    {
        const int r  = tid >> 2;
        const int d0 = (tid & 3) * 32;
        const float* src = latent + ((size_t)b * SS + (m0 + r)) * DD + d0;
        float f[32];
        #pragma unroll
        for (int c = 0; c < 8; ++c)
            *(float4*)(f + 4 * c) = ((const float4*)src)[c];
        #pragma unroll
        for (int c = 0; c < 4; ++c) {
            short tmp[8];
            #pragma unroll
            for (int e = 0; e < 8; ++e) tmp[e] = f2bf(f[c * 8 + e]);
            *(bf16x8*)(ldsA + lds_off(r, d0 + c * 8)) = *(bf16x8*)tmp;
        }
    }
    {
        const int c   = tid >> 2;
        const int d0  = (tid & 3) * 32;
        const int col = n0 + c;
        const int j   = col >> 4;
        const int k   = col & 15;
        const int idx = (k < 15) ? samples[(size_t)b * (SS * (KK - 1)) + j * (KK - 1) + k]
                                 : labels[b * SS + j];
        const float* src = embed + (size_t)idx * DD + d0;
        float f[32];
        #pragma unroll
        for (int cc = 0; cc < 8; ++cc)
            *(float4*)(f + 4 * cc) = ((const float4*)src)[cc];
        #pragma unroll
        for (int cc = 0; cc < 4; ++cc) {
            short tmp[8];
            #pragma unroll
            for (int e = 0; e < 8; ++e) tmp[e] = f2bf(f[cc * 8 + e]);
            *(bf16x8*)(ldsB + lds_off(c, d0 + cc * 8)) = *(bf16x8*)tmp;
        }
    }
    __syncthreads();

    const int wave = tid >> 6;
    const int lane = tid & 63;
    const int wm = wave >> 1, wn = wave & 1;
    const int lr = lane & 15;
    const int lk = (lane >> 4) * 8;
    const int sub = lane >> 4;

    f32x4 acc[2][2] = {};
    #pragma unroll
    for (int ks = 0; ks < 4; ++ks) {
        const int d = ks * 32 + lk;
        bf16x8 a[2], bb2[2];
        #pragma unroll
        for (int mf = 0; mf < 2; ++mf)
            a[mf] = *(const bf16x8*)(ldsA + lds_off(wm * 32 + mf * 16 + lr, d));
        #pragma unroll
        for (int nf = 0; nf < 2; ++nf)
            bb2[nf] = *(const bf16x8*)(ldsB + lds_off(wn * 32 + nf * 16 + lr, d));
        #pragma unroll
        for (int mf = 0; mf < 2; ++mf)
            #pragma unroll
            for (int nf = 0; nf < 2; ++nf)
                acc[mf][nf] = __builtin_amdgcn_mfma_f32_16x16x32_bf16(
                    bb2[nf], a[mf], acc[mf][nf], 0, 0, 0);
    }

    #pragma unroll
    for (int mf = 0; mf < 2; ++mf) {
        #pragma unroll
        for (int nf = 0; nf < 2; ++nf) {
            const f32x4 v = acc[mf][nf];
            float mx = fmaxf(fmaxf(v[0], v[1]), fmaxf(v[2], v[3]));
            mx = fmaxf(mx, __shfl_xor(mx, 16));
            mx = fmaxf(mx, __shfl_xor(mx, 32));
            float e = __expf(v[0] - mx) + __expf(v[1] - mx)
                    + __expf(v[2] - mx) + __expf(v[3] - mx);
            e += __shfl_xor(e, 16);
            e += __shfl_xor(e, 32);
            float pos = __shfl(v[3], (lane & 15) | 48);
            if (sub == 0) {
                const int i  = m0 + wm * 32 + mf * 16 + (lane & 15);
                const int jj = (n0 >> 4) + wn * 2 + nf;
                out[((size_t)b * SS + i) * SS + jj] = pos - mx - __logf(e);
            }
        }
    }
}

extern "C" void kernel_launch(void* const* d_in, const int* in_sizes, int n_in,
                              void* d_out, int out_size, void* d_ws, size_t ws_size,
                              hipStream_t stream) {
    const float* latent  = (const float*)d_in[0];
    const int*   labels  = (const int*)d_in[1];
    const int*   samples = (const int*)d_in[2];
    const float* embed   = (const float*)d_in[3];
    float* out = (float*)d_out;

    const size_t ws_needed = (size_t)NLAT * 2;
    if (ws_size >= ws_needed) {
        ushort_t* ws_lat = (ushort_t*)d_ws;
        convert_lat_kernel<<<(NCHUNK_LAT + 255) / 256, 256, 0, stream>>>(
            latent, ws_lat);
        dim3 grid(SK / NT, SS / MTB, BB);
        neg_loss_main<<<grid, dim3(256), 0, stream>>>(
            ws_lat, labels, samples, embed, out);
    } else {
        dim3 grid(SK / 64, SS / 64, BB);
        neg_loss_fallback<<<grid, dim3(256), 0, stream>>>(
            latent, labels, samples, embed, out);
    }
}